// Round 16
// baseline (152.789 us; speedup 1.0000x reference)
//
#include <hip/hip_runtime.h>
#include <stdint.h>

typedef unsigned short u16;
typedef unsigned int   u32;
typedef __attribute__((ext_vector_type(8)))  short short8;
typedef __attribute__((ext_vector_type(2)))  float f32x2;
typedef __attribute__((ext_vector_type(4)))  float f32x4;
typedef __attribute__((ext_vector_type(16))) float f32x16;

#define NTOK 4096
#define LOG2E 1.44269504088896340736f
#define QS    (0.125f * LOG2E)

// round-to-nearest-even f32 -> bf16
__device__ __forceinline__ u16 f2bf(float f) {
    u32 u = __builtin_bit_cast(u32, f);
    u += 0x7fffu + ((u >> 16) & 1u);
    return (u16)(u >> 16);
}
__device__ __forceinline__ float bf2f(u16 v) {
    return __builtin_bit_cast(float, (u32)v << 16);
}
// gfx950 packed f32->bf16 convert (RNE), 1 VALU op: {lo: bf16(a), hi: bf16(b)}
__device__ __forceinline__ u32 cvtpk(float a, float b) {
    u32 r;
    asm("v_cvt_pk_bf16_f32 %0, %1, %2" : "=v"(r) : "v"(a), "v"(b));
    return r;
}
// gfx950 cross-half swap (VALU, no LDS pipe): after call,
// a = {a.lanes0-31, b.lanes0-31}, b = {a.lanes32-63, b.lanes32-63}
__device__ __forceinline__ void pl32swap(u32 &a, u32 &b) {
    asm("v_permlane32_swap_b32 %0, %1" : "+v"(a), "+v"(b));
}
__device__ __forceinline__ f32x16 zero16() {
    f32x16 v;
#pragma unroll
    for (int i = 0; i < 16; ++i) v[i] = 0.f;
    return v;
}

#define MFMA16x32 __builtin_amdgcn_mfma_f32_16x16x32_bf16
#define MFMA32x16 __builtin_amdgcn_mfma_f32_32x32x16_bf16

// ---------------- kernel 1: QKV projection via MFMA (frozen from R12/R19) ----------------
// K and V stored FRAG-PACKED: every attn fragment load is a contiguous 1KB
// wave load (16 L2 line-requests, minimum) -- R12 proved this is worth 1.3x.
// R21's LDS-staged coalesced stores were NULL (123.0 vs 121.3) -> reverted.
__global__ __launch_bounds__(256) void qkv_mfma5(
    const float* __restrict__ x,
    const float* __restrict__ wq, const float* __restrict__ bq,
    const float* __restrict__ wk, const float* __restrict__ bk,
    const float* __restrict__ wv, const float* __restrict__ bv,
    u16* __restrict__ Q, u16* __restrict__ KF, u16* __restrict__ VF)
{
    __shared__ __align__(16) u16 Wl[3 * 64 * 72];
    __shared__ __align__(16) u16 Xl[64 * 64];
    const int tid  = threadIdx.x;
    const int b    = blockIdx.x & 7;
    const int slab = blockIdx.x >> 3;
    const int n0   = slab << 6;
    const int wave = tid >> 6;
    const int lane = tid & 63;
    const int quad = lane >> 4;
    const int l15  = lane & 15;

#pragma unroll
    for (int j = 0; j < 12; ++j) {
        const float* src = (j < 4) ? wq : (j < 8) ? wk : wv;
        const float sc = (j < 4) ? QS : 1.0f;
        const int idx = (j & 3) * 1024 + tid * 4;
        const float4 v = *(const float4*)(src + idx);
        uint2 pk;
        pk.x = (u32)f2bf(v.x * sc) | ((u32)f2bf(v.y * sc) << 16);
        pk.y = (u32)f2bf(v.z * sc) | ((u32)f2bf(v.w * sc) << 16);
        *(uint2*)&Wl[(j >> 2) * 4608 + (idx >> 6) * 72 + (idx & 63)] = pk;
    }

    float4 xs[4];
#pragma unroll
    for (int g = 0; g < 4; ++g) {
        const int ch = g * 16 + wave * 4 + quad;
        xs[g] = *(const float4*)(x + ((size_t)(b * 64 + ch)) * NTOK + n0 + l15 * 4);
    }
#pragma unroll
    for (int g = 0; g < 4; ++g) {
        const int ch = g * 16 + wave * 4 + quad;
        const float vv[4] = {xs[g].x, xs[g].y, xs[g].z, xs[g].w};
#pragma unroll
        for (int e = 0; e < 4; ++e) {
            const int tok = l15 * 4 + e;
            Xl[tok * 64 + (((ch >> 3) ^ (tok & 7)) & 7) * 8 + (ch & 7)] = f2bf(vv[e]);
        }
    }
    __syncthreads();

    const int row0 = wave * 16 + l15;
    short8 xf[2];
#pragma unroll
    for (int kk = 0; kk < 2; ++kk)
        xf[kk] = *(const short8*)&Xl[row0 * 64 + (((kk * 4 + quad) ^ (row0 & 7)) & 7) * 8];

    const size_t tokbase = (size_t)b * NTOK + n0 + wave * 16;

#pragma unroll
    for (int mat = 0; mat < 2; ++mat) {
        const float* bias = (mat == 0) ? bq : bk;
        const float bsc = (mat == 0) ? QS : 1.0f;
#pragma unroll
        for (int mt = 0; mt < 4; ++mt) {
            const u16* wr = &Wl[mat * 4608 + (mt * 16 + l15) * 72 + quad * 8];
            const short8 wf0 = *(const short8*)(wr);
            const short8 wf1 = *(const short8*)(wr + 32);
            f32x4 acc = {0.f, 0.f, 0.f, 0.f};
            acc = MFMA16x32(wf0, xf[0], acc, 0, 0, 0);
            acc = MFMA16x32(wf1, xf[1], acc, 0, 0, 0);
            const float4 b4 = *(const float4*)(bias + mt * 16 + quad * 4);
            uint2 pk;
            pk.x = (u32)f2bf(acc[0] + b4.x * bsc) | ((u32)f2bf(acc[1] + b4.y * bsc) << 16);
            pk.y = (u32)f2bf(acc[2] + b4.z * bsc) | ((u32)f2bf(acc[3] + b4.w * bsc) << 16);
            if (mat == 0) {
                *(uint2*)(Q + (tokbase + l15) * 64 + mt * 16 + quad * 4) = pk;
            } else {
                const int tokl = wave * 16 + l15;
                const int gt   = slab * 2 + (tokl >> 5);
                const int c31k = tokl & 31;
                const int hwk  = quad >> 1;
                const int j0   = (quad & 1) * 4;
                *(uint2*)(KF + (((size_t)b * 128 + gt) * 4 + mt) * 512
                             + (hwk * 32 + c31k) * 8 + j0) = pk;
            }
        }
    }

    __syncthreads();
    u16* Vl = Xl;
    const int tok = wave * 16 + l15;
#pragma unroll
    for (int mt = 0; mt < 4; ++mt) {
        const u16* wr = &Wl[2 * 4608 + (mt * 16 + l15) * 72 + quad * 8];
        const short8 wf0 = *(const short8*)(wr);
        const short8 wf1 = *(const short8*)(wr + 32);
        f32x4 acc = {0.f, 0.f, 0.f, 0.f};
        acc = MFMA16x32(wf0, xf[0], acc, 0, 0, 0);
        acc = MFMA16x32(wf1, xf[1], acc, 0, 0, 0);
        const float4 b4 = *(const float4*)(bv + mt * 16 + quad * 4);
        const float o[4] = {acc[0] + b4.x, acc[1] + b4.y, acc[2] + b4.z, acc[3] + b4.w};
#pragma unroll
        for (int r = 0; r < 4; ++r) {
            const int d = mt * 16 + quad * 4 + r;
            Vl[d * 64 + (((tok >> 3) ^ ((d >> 1) & 7)) & 7) * 8 + (tok & 7)] = f2bf(o[r]);
        }
    }
    __syncthreads();

#pragma unroll
    for (int dd = 0; dd < 4; ++dd) {
        const int d2   = (tid >> 4) + dd * 16;
        const int tok0 = (tid & 15) * 4;
        const int slot = ((tok0 >> 3) ^ ((d2 >> 1) & 7)) & 7;
        const uint2 v2 = *(const uint2*)&Vl[d2 * 64 + slot * 8 + (tok0 & 7)];
        const int gt  = slab * 2 + (tok0 >> 5);
        const int mk  = ((d2 >> 5) << 1) | ((tok0 & 31) >> 4);
        const int hwv = (tok0 >> 3) & 1;
        const int j   = tok0 & 7;
        *(uint2*)(VF + (((size_t)b * 128 + gt) * 4 + mk) * 512
                     + (hwv * 32 + (d2 & 31)) * 8 + j) = v2;
    }
}

// ---------------- kernel 2: fused attention + mix + 2x2 pool ----------------
// R22 = R19 (best: attn 45.0us, bench 121.35) with the prefetch rotation
// deepened 3 -> 4 buffers. Rationale: depth is the one attn lever with a
// measured positive track record (2->3 deep was 53->49, R13->R14 isolated)
// and the stall signature (both pipes <40%, 14us unexplained) is consistent
// with remaining L2-under-load latency exposure. Register check vs MEASURED
// baselines: R19 = 128 arch + 64 acc with 3 pairs; +1 pair = +32 arch ->
// 224 <= 256 cap at (512,2), 32 spare, no occupancy loss. Loop: 7 iters x 4
// stages + 4 clamped tail stages = 32 tiles. stage body / tail / epilogue
// byte-identical to R19 (setprio-free). Markers: VGPR ~155-165 = 4th buffer
// live (success); ~128 = sunk (null); regression -> revert R19.
__global__ __launch_bounds__(512, 2) void attn20(
    const u16* __restrict__ Q, const u16* __restrict__ KF,
    const u16* __restrict__ VF,
    const float* __restrict__ wm, const float* __restrict__ bm,
    float* __restrict__ out)
{
    __shared__ __align__(16) char smem[54272];
    const int tid  = threadIdx.x;
    const int wave = tid >> 6;
    const int lane = tid & 63;
    const int c31  = lane & 31;
    const int hw   = lane >> 5;          // half-wave
    const int quad = lane >> 4;
    const int l15  = lane & 15;
    const int h    = wave >> 2;          // Q half (64 rows)
    const int s    = wave & 3;           // KV slice (1024 tokens)
    const int b    = blockIdx.x & 7;
    const int oh   = blockIdx.x >> 3;
    const int n0   = oh * 128;

    // Q B-frags: B[k=ch][n=qrow]: lane (c31,hw) reads Q[qrow=nt*32+c31][ks*16+hw*8+j]
    short8 qf[2][4];
#pragma unroll
    for (int nt = 0; nt < 2; ++nt)
#pragma unroll
        for (int ks = 0; ks < 4; ++ks)
            qf[nt][ks] = *(const short8*)(Q + ((size_t)(b * NTOK + n0 + h * 64 + nt * 32 + c31)) * 64
                                            + ks * 16 + hw * 8);

    const u16* KFb = KF + ((size_t)b * 128 + s * 32) * 2048;
    const u16* VFb = VF + ((size_t)b * 128 + s * 32) * 2048;
    const int l8 = lane * 8;             // u16 offset of this lane's 16B frag chunk

    f32x16 O[2][2];                       // [mt][nt] = O^T tiles, 64 AGPR
#pragma unroll
    for (int mt = 0; mt < 2; ++mt)
#pragma unroll
        for (int nt = 0; nt < 2; ++nt) O[mt][nt] = zero16();
    float lpa[2] = {0.f, 0.f};

    auto load_k = [&](short8 (&kf)[4], int t) {
        const int tc = (t < 32) ? t : 31;
        const u16* kt = KFb + (size_t)tc * 2048;
#pragma unroll
        for (int ks = 0; ks < 4; ++ks)
            kf[ks] = *(const short8*)(kt + ks * 512 + l8);
    };
    auto load_v = [&](short8 (&vf)[4], int t) {
        const int tc = (t < 32) ? t : 31;
        const u16* vt = VFb + (size_t)tc * 2048;
#pragma unroll
        for (int mk = 0; mk < 4; ++mk)
            vf[mk] = *(const short8*)(vt + mk * 512 + l8);
    };

    // one pipeline stage: QK on (kf,vf)'s tile, reload kf<-tnext right after
    // QK (kf free), tail (exp/pack/swap/PV), reload vf<-tnext after PV.
    auto stage = [&](short8 (&kf)[4], short8 (&vf)[4], int tnext) {
        f32x16 sv[2];
#pragma unroll
        for (int nt = 0; nt < 2; ++nt) {
            f32x16 a = zero16();
            a = MFMA32x16(kf[0], qf[nt][0], a, 0, 0, 0);
            a = MFMA32x16(kf[1], qf[nt][1], a, 0, 0, 0);
            a = MFMA32x16(kf[2], qf[nt][2], a, 0, 0, 0);
            a = MFMA32x16(kf[3], qf[nt][3], a, 0, 0, 0);
            sv[nt] = a;
        }
        load_k(kf, tnext);                     // ~3.3 stages of slack
        __builtin_amdgcn_sched_barrier(0);
#pragma unroll
        for (int nt = 0; nt < 2; ++nt) {
            float p[16];
#pragma unroll
            for (int r = 0; r < 16; ++r) p[r] = __builtin_amdgcn_exp2f(sv[nt][r]);
            const f32x2 a0 = {p[0],  p[1]},  a1 = {p[2],  p[3]};
            const f32x2 a2 = {p[4],  p[5]},  a3 = {p[6],  p[7]};
            const f32x2 a4 = {p[8],  p[9]},  a5 = {p[10], p[11]};
            const f32x2 a6 = {p[12], p[13]}, a7 = {p[14], p[15]};
            const f32x2 s0 = a0 + a1, s1 = a2 + a3, s2 = a4 + a5, s3 = a6 + a7;
            const f32x2 s4 = s0 + s1, s5 = s2 + s3;
            const f32x2 s6 = s4 + s5;
            lpa[nt] += s6.x + s6.y;
            u32 c0 = cvtpk(p[0],  p[1]),  c1 = cvtpk(p[2],  p[3]);
            u32 c2 = cvtpk(p[4],  p[5]),  c3 = cvtpk(p[6],  p[7]);
            u32 c4 = cvtpk(p[8],  p[9]),  c5 = cvtpk(p[10], p[11]);
            u32 c6 = cvtpk(p[12], p[13]), c7 = cvtpk(p[14], p[15]);
            pl32swap(c0, c2);  pl32swap(c1, c3);
            pl32swap(c4, c6);  pl32swap(c5, c7);
            uint4 B0, B1;                 // P^T B-frags, k-windows 0-15 / 16-31
            B0.x = c0; B0.y = c1; B0.z = c2; B0.w = c3;
            B1.x = c4; B1.y = c5; B1.z = c6; B1.w = c7;
            const short8 pb0 = __builtin_bit_cast(short8, B0);
            const short8 pb1 = __builtin_bit_cast(short8, B1);
            O[0][nt] = MFMA32x16(vf[0], pb0, O[0][nt], 0, 0, 0);
            O[0][nt] = MFMA32x16(vf[1], pb1, O[0][nt], 0, 0, 0);
            O[1][nt] = MFMA32x16(vf[2], pb0, O[1][nt], 0, 0, 0);
            O[1][nt] = MFMA32x16(vf[3], pb1, O[1][nt], 0, 0, 0);
        }
        load_v(vf, tnext);                     // ~3 stages of slack
        __builtin_amdgcn_sched_barrier(0);
    };

    short8 kf0[4], vf0[4], kf1[4], vf1[4], kf2[4], vf2[4], kf3[4], vf3[4];
    load_k(kf0, 0); load_v(vf0, 0);
    load_k(kf1, 1); load_v(vf1, 1);
    load_k(kf2, 2); load_v(vf2, 2);
    load_k(kf3, 3); load_v(vf3, 3);

#pragma unroll 1
    for (int tt = 0; tt < 7; ++tt) {
        const int t0 = tt * 4;
        stage(kf0, vf0, t0 + 4);
        stage(kf1, vf1, t0 + 5);
        stage(kf2, vf2, t0 + 6);
        stage(kf3, vf3, t0 + 7);
    }
    stage(kf0, vf0, 31);   // tile 28 (prefetch clamped, unused)
    stage(kf1, vf1, 31);   // tile 29
    stage(kf2, vf2, 31);   // tile 30
    stage(kf3, vf3, 31);   // tile 31

    // ---- epilogue ----
    // combine lp halves (disjoint token sets), lane (c31,*) -> lp[qrow nt*32+c31]
#pragma unroll
    for (int nt = 0; nt < 2; ++nt) lpa[nt] += __shfl_xor(lpa[nt], 32);

    float* lpbuf = (float*)(smem + 52224);
    if (hw == 0) {
#pragma unroll
        for (int nt = 0; nt < 2; ++nt)
            lpbuf[(h * 4 + s) * 64 + nt * 32 + c31] = lpa[nt];
    }
    if (s != 0) {                          // bf16 O-partial sections
        u16* sec = (u16*)smem + (h * 3 + s - 1) * 4352;
#pragma unroll
        for (int mt = 0; mt < 2; ++mt)
#pragma unroll
            for (int nt = 0; nt < 2; ++nt)
#pragma unroll
                for (int r = 0; r < 16; ++r) {
                    const int ch = mt * 32 + (r & 3) + 8 * (r >> 2) + 4 * hw;
                    sec[(nt * 32 + c31) * 68 + ch] = f2bf(O[mt][nt][r]);
                }
    }
    __syncthreads();   // B2: all partials visible

    float rinv[2];
    if (s == 0) {
#pragma unroll
        for (int nt = 0; nt < 2; ++nt) {
            float sum = 0.f;
#pragma unroll
            for (int sx = 0; sx < 4; ++sx)
                sum += lpbuf[(h * 4 + sx) * 64 + nt * 32 + c31];
            rinv[nt] = 1.0f / sum;
        }
#pragma unroll
        for (int sx = 1; sx < 4; ++sx) {
            const u16* sec = (const u16*)smem + (h * 3 + sx - 1) * 4352;
#pragma unroll
            for (int mt = 0; mt < 2; ++mt)
#pragma unroll
                for (int nt = 0; nt < 2; ++nt)
#pragma unroll
                    for (int r = 0; r < 16; ++r) {
                        const int ch = mt * 32 + (r & 3) + 8 * (r >> 2) + 4 * hw;
                        O[mt][nt][r] += bf2f(sec[(nt * 32 + c31) * 68 + ch]);
                    }
        }
    }
    // all waves: convert wm -> bf16 B-frags + bias (global reads, overlaps reduction)
    short8 wB[4][2];
    float bb[4];
#pragma unroll
    for (int nt = 0; nt < 4; ++nt) {
        const int d = nt * 16 + l15;
        const float* wr = wm + (size_t)d * 64 + quad * 8;
        const float4 a0 = *(const float4*)(wr);
        const float4 a1 = *(const float4*)(wr + 4);
        const float4 c0 = *(const float4*)(wr + 32);
        const float4 c1 = *(const float4*)(wr + 36);
        ((u32*)&wB[nt][0])[0] = (u32)f2bf(a0.x) | ((u32)f2bf(a0.y) << 16);
        ((u32*)&wB[nt][0])[1] = (u32)f2bf(a0.z) | ((u32)f2bf(a0.w) << 16);
        ((u32*)&wB[nt][0])[2] = (u32)f2bf(a1.x) | ((u32)f2bf(a1.y) << 16);
        ((u32*)&wB[nt][0])[3] = (u32)f2bf(a1.z) | ((u32)f2bf(a1.w) << 16);
        ((u32*)&wB[nt][1])[0] = (u32)f2bf(c0.x) | ((u32)f2bf(c0.y) << 16);
        ((u32*)&wB[nt][1])[1] = (u32)f2bf(c0.z) | ((u32)f2bf(c0.w) << 16);
        ((u32*)&wB[nt][1])[2] = (u32)f2bf(c1.x) | ((u32)f2bf(c1.y) << 16);
        ((u32*)&wB[nt][1])[3] = (u32)f2bf(c1.z) | ((u32)f2bf(c1.w) << 16);
        bb[nt] = bm[d];
    }
    __syncthreads();   // B3: section reads done; M0 may overlay

    if (s == 0) {      // normalize -> M0 bf16 (swizzled [qrow][ch]) at h*8KB
        u16* M0 = (u16*)smem + h * 4096;
#pragma unroll
        for (int mt = 0; mt < 2; ++mt)
#pragma unroll
            for (int nt = 0; nt < 2; ++nt)
#pragma unroll
                for (int r = 0; r < 16; ++r) {
                    const int lr = nt * 32 + c31;
                    const int ch = mt * 32 + (r & 3) + 8 * (r >> 2) + 4 * hw;
                    const float v = O[mt][nt][r] * rinv[nt];
                    M0[lr * 64 + (((ch >> 3) ^ (lr & 7)) & 7) * 8 + (ch & 7)] = f2bf(v);
                }
    }
    __syncthreads();   // B4

    // mix: wave w handles rows [16w, 16w+16) (R7-proven)
    const u16* M0r = (const u16*)smem + (wave >> 2) * 4096;
    const int lr = (wave & 3) * 16 + l15;
    const short8 af0 = *(const short8*)&M0r[lr * 64 + ((quad ^ (lr & 7)) & 7) * 8];
    const short8 af1 = *(const short8*)&M0r[lr * 64 + (((4 + quad) ^ (lr & 7)) & 7) * 8];
    float* Mf = (float*)(smem + 16384);      // [128][68] fp32, disjoint from M0
#pragma unroll
    for (int nt = 0; nt < 4; ++nt) {
        f32x4 acc = {0.f, 0.f, 0.f, 0.f};
        acc = MFMA16x32(af0, wB[nt][0], acc, 0, 0, 0);
        acc = MFMA16x32(af1, wB[nt][1], acc, 0, 0, 0);
#pragma unroll
        for (int r = 0; r < 4; ++r) {
            float v = acc[r] + bb[nt];
            v = v > 0.f ? v : 0.f;
            Mf[(wave * 16 + quad * 4 + r) * 68 + nt * 16 + l15] = v;
        }
    }
    __syncthreads();   // B5

    // 2x2 avg pool (== bilinear 2x downsample, half-pixel)
    const int ow = tid & 31;
    const int cb = (tid >> 5) & 15;
#pragma unroll
    for (int i = 0; i < 4; ++i) {
        const int c = cb + i * 16;
        const float v = 0.25f * (Mf[(2 * ow) * 68 + c] + Mf[(2 * ow + 1) * 68 + c]
                               + Mf[(64 + 2 * ow) * 68 + c] + Mf[(65 + 2 * ow) * 68 + c]);
        out[((size_t)(b * 64 + c) * 32 + oh) * 32 + ow] = v;
    }
}

extern "C" void kernel_launch(void* const* d_in, const int* in_sizes, int n_in,
                              void* d_out, int out_size, void* d_ws, size_t ws_size,
                              hipStream_t stream) {
    (void)in_sizes; (void)n_in; (void)out_size; (void)ws_size;
    const float* x  = (const float*)d_in[0];
    const float* wq = (const float*)d_in[1];
    const float* bq = (const float*)d_in[2];
    const float* wk = (const float*)d_in[3];
    const float* bk = (const float*)d_in[4];
    const float* wv = (const float*)d_in[5];
    const float* bv = (const float*)d_in[6];
    const float* wm = (const float*)d_in[7];
    const float* bm = (const float*)d_in[8];

    // ws: Q bf16 [8][4096][64] | KF bf16 [8][128][4][512] | VF bf16 [8][128][4][512] = 12 MB
    u16* Q  = (u16*)d_ws;
    u16* KF = Q + (size_t)8 * NTOK * 64;
    u16* VF = KF + (size_t)8 * NTOK * 64;

    qkv_mfma5<<<512, 256, 0, stream>>>(x, wq, bq, wk, bk, wv, bv, Q, KF, VF);
    attn20<<<256, 512, 0, stream>>>(Q, KF, VF, wm, bm, (float*)d_out);
}

// Round 17
// 121.549 us; speedup vs baseline: 1.2570x; 1.2570x over previous
//
#include <hip/hip_runtime.h>
#include <stdint.h>

typedef unsigned short u16;
typedef unsigned int   u32;
typedef __attribute__((ext_vector_type(8)))  short short8;
typedef __attribute__((ext_vector_type(2)))  float f32x2;
typedef __attribute__((ext_vector_type(4)))  float f32x4;
typedef __attribute__((ext_vector_type(16))) float f32x16;

#define NTOK 4096
#define LOG2E 1.44269504088896340736f
#define QS    (0.125f * LOG2E)

// round-to-nearest-even f32 -> bf16
__device__ __forceinline__ u16 f2bf(float f) {
    u32 u = __builtin_bit_cast(u32, f);
    u += 0x7fffu + ((u >> 16) & 1u);
    return (u16)(u >> 16);
}
__device__ __forceinline__ float bf2f(u16 v) {
    return __builtin_bit_cast(float, (u32)v << 16);
}
// gfx950 packed f32->bf16 convert (RNE), 1 VALU op: {lo: bf16(a), hi: bf16(b)}
__device__ __forceinline__ u32 cvtpk(float a, float b) {
    u32 r;
    asm("v_cvt_pk_bf16_f32 %0, %1, %2" : "=v"(r) : "v"(a), "v"(b));
    return r;
}
// gfx950 cross-half swap (VALU, no LDS pipe): after call,
// a = {a.lanes0-31, b.lanes0-31}, b = {a.lanes32-63, b.lanes32-63}
__device__ __forceinline__ void pl32swap(u32 &a, u32 &b) {
    asm("v_permlane32_swap_b32 %0, %1" : "+v"(a), "+v"(b));
}
__device__ __forceinline__ f32x16 zero16() {
    f32x16 v;
#pragma unroll
    for (int i = 0; i < 16; ++i) v[i] = 0.f;
    return v;
}

#define MFMA16x32 __builtin_amdgcn_mfma_f32_16x16x32_bf16
#define MFMA32x16 __builtin_amdgcn_mfma_f32_32x32x16_bf16

// ---------------- kernel 1: QKV projection via MFMA (frozen from R12/R19) ----------------
// K and V stored FRAG-PACKED: every attn fragment load is a contiguous 1KB
// wave load (16 L2 line-requests, minimum) -- R12 proved this is worth 1.3x.
__global__ __launch_bounds__(256) void qkv_mfma5(
    const float* __restrict__ x,
    const float* __restrict__ wq, const float* __restrict__ bq,
    const float* __restrict__ wk, const float* __restrict__ bk,
    const float* __restrict__ wv, const float* __restrict__ bv,
    u16* __restrict__ Q, u16* __restrict__ KF, u16* __restrict__ VF)
{
    __shared__ __align__(16) u16 Wl[3 * 64 * 72];
    __shared__ __align__(16) u16 Xl[64 * 64];
    const int tid  = threadIdx.x;
    const int b    = blockIdx.x & 7;
    const int slab = blockIdx.x >> 3;
    const int n0   = slab << 6;
    const int wave = tid >> 6;
    const int lane = tid & 63;
    const int quad = lane >> 4;
    const int l15  = lane & 15;

#pragma unroll
    for (int j = 0; j < 12; ++j) {
        const float* src = (j < 4) ? wq : (j < 8) ? wk : wv;
        const float sc = (j < 4) ? QS : 1.0f;
        const int idx = (j & 3) * 1024 + tid * 4;
        const float4 v = *(const float4*)(src + idx);
        uint2 pk;
        pk.x = (u32)f2bf(v.x * sc) | ((u32)f2bf(v.y * sc) << 16);
        pk.y = (u32)f2bf(v.z * sc) | ((u32)f2bf(v.w * sc) << 16);
        *(uint2*)&Wl[(j >> 2) * 4608 + (idx >> 6) * 72 + (idx & 63)] = pk;
    }

    float4 xs[4];
#pragma unroll
    for (int g = 0; g < 4; ++g) {
        const int ch = g * 16 + wave * 4 + quad;
        xs[g] = *(const float4*)(x + ((size_t)(b * 64 + ch)) * NTOK + n0 + l15 * 4);
    }
#pragma unroll
    for (int g = 0; g < 4; ++g) {
        const int ch = g * 16 + wave * 4 + quad;
        const float vv[4] = {xs[g].x, xs[g].y, xs[g].z, xs[g].w};
#pragma unroll
        for (int e = 0; e < 4; ++e) {
            const int tok = l15 * 4 + e;
            Xl[tok * 64 + (((ch >> 3) ^ (tok & 7)) & 7) * 8 + (ch & 7)] = f2bf(vv[e]);
        }
    }
    __syncthreads();

    const int row0 = wave * 16 + l15;
    short8 xf[2];
#pragma unroll
    for (int kk = 0; kk < 2; ++kk)
        xf[kk] = *(const short8*)&Xl[row0 * 64 + (((kk * 4 + quad) ^ (row0 & 7)) & 7) * 8];

    const size_t tokbase = (size_t)b * NTOK + n0 + wave * 16;

#pragma unroll
    for (int mat = 0; mat < 2; ++mat) {
        const float* bias = (mat == 0) ? bq : bk;
        const float bsc = (mat == 0) ? QS : 1.0f;
#pragma unroll
        for (int mt = 0; mt < 4; ++mt) {
            const u16* wr = &Wl[mat * 4608 + (mt * 16 + l15) * 72 + quad * 8];
            const short8 wf0 = *(const short8*)(wr);
            const short8 wf1 = *(const short8*)(wr + 32);
            f32x4 acc = {0.f, 0.f, 0.f, 0.f};
            acc = MFMA16x32(wf0, xf[0], acc, 0, 0, 0);
            acc = MFMA16x32(wf1, xf[1], acc, 0, 0, 0);
            const float4 b4 = *(const float4*)(bias + mt * 16 + quad * 4);
            uint2 pk;
            pk.x = (u32)f2bf(acc[0] + b4.x * bsc) | ((u32)f2bf(acc[1] + b4.y * bsc) << 16);
            pk.y = (u32)f2bf(acc[2] + b4.z * bsc) | ((u32)f2bf(acc[3] + b4.w * bsc) << 16);
            if (mat == 0) {
                *(uint2*)(Q + (tokbase + l15) * 64 + mt * 16 + quad * 4) = pk;
            } else {
                const int tokl = wave * 16 + l15;
                const int gt   = slab * 2 + (tokl >> 5);
                const int c31k = tokl & 31;
                const int hwk  = quad >> 1;
                const int j0   = (quad & 1) * 4;
                *(uint2*)(KF + (((size_t)b * 128 + gt) * 4 + mt) * 512
                             + (hwk * 32 + c31k) * 8 + j0) = pk;
            }
        }
    }

    __syncthreads();
    u16* Vl = Xl;
    const int tok = wave * 16 + l15;
#pragma unroll
    for (int mt = 0; mt < 4; ++mt) {
        const u16* wr = &Wl[2 * 4608 + (mt * 16 + l15) * 72 + quad * 8];
        const short8 wf0 = *(const short8*)(wr);
        const short8 wf1 = *(const short8*)(wr + 32);
        f32x4 acc = {0.f, 0.f, 0.f, 0.f};
        acc = MFMA16x32(wf0, xf[0], acc, 0, 0, 0);
        acc = MFMA16x32(wf1, xf[1], acc, 0, 0, 0);
        const float4 b4 = *(const float4*)(bv + mt * 16 + quad * 4);
        const float o[4] = {acc[0] + b4.x, acc[1] + b4.y, acc[2] + b4.z, acc[3] + b4.w};
#pragma unroll
        for (int r = 0; r < 4; ++r) {
            const int d = mt * 16 + quad * 4 + r;
            Vl[d * 64 + (((tok >> 3) ^ ((d >> 1) & 7)) & 7) * 8 + (tok & 7)] = f2bf(o[r]);
        }
    }
    __syncthreads();

#pragma unroll
    for (int dd = 0; dd < 4; ++dd) {
        const int d2   = (tid >> 4) + dd * 16;
        const int tok0 = (tid & 15) * 4;
        const int slot = ((tok0 >> 3) ^ ((d2 >> 1) & 7)) & 7;
        const uint2 v2 = *(const uint2*)&Vl[d2 * 64 + slot * 8 + (tok0 & 7)];
        const int gt  = slab * 2 + (tok0 >> 5);
        const int mk  = ((d2 >> 5) << 1) | ((tok0 & 31) >> 4);
        const int hwv = (tok0 >> 3) & 1;
        const int j   = tok0 & 7;
        *(uint2*)(VF + (((size_t)b * 128 + gt) * 4 + mk) * 512
                     + (hwv * 32 + (d2 & 31)) * 8 + j) = v2;
    }
}

// ---------------- kernel 2: fused attention + mix + 2x2 pool ----------------
// R23 = R19 RESTORED byte-exact (verified best: bench 121.35us, attn 45.0us).
// R22's 4-deep rotation spilled (VGPR pinned 128, WRITE 130MB scratch) --
// depth 3 is the register-feasible max at (512,2). Final configuration:
// setprio-free 3-deep prefetch rotation, frag-packed contiguous 1KB K/V
// loads (R12), cvtpk/pl32swap in-register softmax exchange (R13), R7-proven
// epilogue. Session: 137.2 -> 121.3 bench (1.13x), attn 65.6 -> 45.0 (1.46x).
__global__ __launch_bounds__(512, 2) void attn19(
    const u16* __restrict__ Q, const u16* __restrict__ KF,
    const u16* __restrict__ VF,
    const float* __restrict__ wm, const float* __restrict__ bm,
    float* __restrict__ out)
{
    __shared__ __align__(16) char smem[54272];
    const int tid  = threadIdx.x;
    const int wave = tid >> 6;
    const int lane = tid & 63;
    const int c31  = lane & 31;
    const int hw   = lane >> 5;          // half-wave
    const int quad = lane >> 4;
    const int l15  = lane & 15;
    const int h    = wave >> 2;          // Q half (64 rows)
    const int s    = wave & 3;           // KV slice (1024 tokens)
    const int b    = blockIdx.x & 7;
    const int oh   = blockIdx.x >> 3;
    const int n0   = oh * 128;

    // Q B-frags: B[k=ch][n=qrow]: lane (c31,hw) reads Q[qrow=nt*32+c31][ks*16+hw*8+j]
    short8 qf[2][4];
#pragma unroll
    for (int nt = 0; nt < 2; ++nt)
#pragma unroll
        for (int ks = 0; ks < 4; ++ks)
            qf[nt][ks] = *(const short8*)(Q + ((size_t)(b * NTOK + n0 + h * 64 + nt * 32 + c31)) * 64
                                            + ks * 16 + hw * 8);

    const u16* KFb = KF + ((size_t)b * 128 + s * 32) * 2048;
    const u16* VFb = VF + ((size_t)b * 128 + s * 32) * 2048;
    const int l8 = lane * 8;             // u16 offset of this lane's 16B frag chunk

    f32x16 O[2][2];                       // [mt][nt] = O^T tiles, 64 AGPR
#pragma unroll
    for (int mt = 0; mt < 2; ++mt)
#pragma unroll
        for (int nt = 0; nt < 2; ++nt) O[mt][nt] = zero16();
    float lpa[2] = {0.f, 0.f};

    auto load_k = [&](short8 (&kf)[4], int t) {
        const int tc = (t < 32) ? t : 31;
        const u16* kt = KFb + (size_t)tc * 2048;
#pragma unroll
        for (int ks = 0; ks < 4; ++ks)
            kf[ks] = *(const short8*)(kt + ks * 512 + l8);
    };
    auto load_v = [&](short8 (&vf)[4], int t) {
        const int tc = (t < 32) ? t : 31;
        const u16* vt = VFb + (size_t)tc * 2048;
#pragma unroll
        for (int mk = 0; mk < 4; ++mk)
            vf[mk] = *(const short8*)(vt + mk * 512 + l8);
    };

    // one pipeline stage: QK on (kf,vf)'s tile, reload kf<-tnext right after
    // QK (kf free), tail (exp/pack/swap/PV), reload vf<-tnext after PV.
    auto stage = [&](short8 (&kf)[4], short8 (&vf)[4], int tnext) {
        f32x16 sv[2];
#pragma unroll
        for (int nt = 0; nt < 2; ++nt) {
            f32x16 a = zero16();
            a = MFMA32x16(kf[0], qf[nt][0], a, 0, 0, 0);
            a = MFMA32x16(kf[1], qf[nt][1], a, 0, 0, 0);
            a = MFMA32x16(kf[2], qf[nt][2], a, 0, 0, 0);
            a = MFMA32x16(kf[3], qf[nt][3], a, 0, 0, 0);
            sv[nt] = a;
        }
        load_k(kf, tnext);                     // ~2.3 stages of slack
        __builtin_amdgcn_sched_barrier(0);
#pragma unroll
        for (int nt = 0; nt < 2; ++nt) {
            float p[16];
#pragma unroll
            for (int r = 0; r < 16; ++r) p[r] = __builtin_amdgcn_exp2f(sv[nt][r]);
            const f32x2 a0 = {p[0],  p[1]},  a1 = {p[2],  p[3]};
            const f32x2 a2 = {p[4],  p[5]},  a3 = {p[6],  p[7]};
            const f32x2 a4 = {p[8],  p[9]},  a5 = {p[10], p[11]};
            const f32x2 a6 = {p[12], p[13]}, a7 = {p[14], p[15]};
            const f32x2 s0 = a0 + a1, s1 = a2 + a3, s2 = a4 + a5, s3 = a6 + a7;
            const f32x2 s4 = s0 + s1, s5 = s2 + s3;
            const f32x2 s6 = s4 + s5;
            lpa[nt] += s6.x + s6.y;
            u32 c0 = cvtpk(p[0],  p[1]),  c1 = cvtpk(p[2],  p[3]);
            u32 c2 = cvtpk(p[4],  p[5]),  c3 = cvtpk(p[6],  p[7]);
            u32 c4 = cvtpk(p[8],  p[9]),  c5 = cvtpk(p[10], p[11]);
            u32 c6 = cvtpk(p[12], p[13]), c7 = cvtpk(p[14], p[15]);
            pl32swap(c0, c2);  pl32swap(c1, c3);
            pl32swap(c4, c6);  pl32swap(c5, c7);
            uint4 B0, B1;                 // P^T B-frags, k-windows 0-15 / 16-31
            B0.x = c0; B0.y = c1; B0.z = c2; B0.w = c3;
            B1.x = c4; B1.y = c5; B1.z = c6; B1.w = c7;
            const short8 pb0 = __builtin_bit_cast(short8, B0);
            const short8 pb1 = __builtin_bit_cast(short8, B1);
            O[0][nt] = MFMA32x16(vf[0], pb0, O[0][nt], 0, 0, 0);
            O[0][nt] = MFMA32x16(vf[1], pb1, O[0][nt], 0, 0, 0);
            O[1][nt] = MFMA32x16(vf[2], pb0, O[1][nt], 0, 0, 0);
            O[1][nt] = MFMA32x16(vf[3], pb1, O[1][nt], 0, 0, 0);
        }
        load_v(vf, tnext);                     // ~2 stages of slack
        __builtin_amdgcn_sched_barrier(0);
    };

    short8 kf0[4], vf0[4], kf1[4], vf1[4], kf2[4], vf2[4];
    load_k(kf0, 0); load_v(vf0, 0);
    load_k(kf1, 1); load_v(vf1, 1);
    load_k(kf2, 2); load_v(vf2, 2);

#pragma unroll 1
    for (int tt = 0; tt < 10; ++tt) {
        const int t0 = tt * 3;
        stage(kf0, vf0, t0 + 3);
        stage(kf1, vf1, t0 + 4);
        stage(kf2, vf2, t0 + 5);
    }
    stage(kf0, vf0, 31);   // tile 30 (prefetch clamped, unused)
    stage(kf1, vf1, 31);   // tile 31 (prefetch clamped, unused)

    // ---- epilogue ----
    // combine lp halves (disjoint token sets), lane (c31,*) -> lp[qrow nt*32+c31]
#pragma unroll
    for (int nt = 0; nt < 2; ++nt) lpa[nt] += __shfl_xor(lpa[nt], 32);

    float* lpbuf = (float*)(smem + 52224);
    if (hw == 0) {
#pragma unroll
        for (int nt = 0; nt < 2; ++nt)
            lpbuf[(h * 4 + s) * 64 + nt * 32 + c31] = lpa[nt];
    }
    if (s != 0) {                          // bf16 O-partial sections
        u16* sec = (u16*)smem + (h * 3 + s - 1) * 4352;
#pragma unroll
        for (int mt = 0; mt < 2; ++mt)
#pragma unroll
            for (int nt = 0; nt < 2; ++nt)
#pragma unroll
                for (int r = 0; r < 16; ++r) {
                    const int ch = mt * 32 + (r & 3) + 8 * (r >> 2) + 4 * hw;
                    sec[(nt * 32 + c31) * 68 + ch] = f2bf(O[mt][nt][r]);
                }
    }
    __syncthreads();   // B2: all partials visible

    float rinv[2];
    if (s == 0) {
#pragma unroll
        for (int nt = 0; nt < 2; ++nt) {
            float sum = 0.f;
#pragma unroll
            for (int sx = 0; sx < 4; ++sx)
                sum += lpbuf[(h * 4 + sx) * 64 + nt * 32 + c31];
            rinv[nt] = 1.0f / sum;
        }
#pragma unroll
        for (int sx = 1; sx < 4; ++sx) {
            const u16* sec = (const u16*)smem + (h * 3 + sx - 1) * 4352;
#pragma unroll
            for (int mt = 0; mt < 2; ++mt)
#pragma unroll
                for (int nt = 0; nt < 2; ++nt)
#pragma unroll
                    for (int r = 0; r < 16; ++r) {
                        const int ch = mt * 32 + (r & 3) + 8 * (r >> 2) + 4 * hw;
                        O[mt][nt][r] += bf2f(sec[(nt * 32 + c31) * 68 + ch]);
                    }
        }
    }
    // all waves: convert wm -> bf16 B-frags + bias (global reads, overlaps reduction)
    short8 wB[4][2];
    float bb[4];
#pragma unroll
    for (int nt = 0; nt < 4; ++nt) {
        const int d = nt * 16 + l15;
        const float* wr = wm + (size_t)d * 64 + quad * 8;
        const float4 a0 = *(const float4*)(wr);
        const float4 a1 = *(const float4*)(wr + 4);
        const float4 c0 = *(const float4*)(wr + 32);
        const float4 c1 = *(const float4*)(wr + 36);
        ((u32*)&wB[nt][0])[0] = (u32)f2bf(a0.x) | ((u32)f2bf(a0.y) << 16);
        ((u32*)&wB[nt][0])[1] = (u32)f2bf(a0.z) | ((u32)f2bf(a0.w) << 16);
        ((u32*)&wB[nt][0])[2] = (u32)f2bf(a1.x) | ((u32)f2bf(a1.y) << 16);
        ((u32*)&wB[nt][0])[3] = (u32)f2bf(a1.z) | ((u32)f2bf(a1.w) << 16);
        ((u32*)&wB[nt][1])[0] = (u32)f2bf(c0.x) | ((u32)f2bf(c0.y) << 16);
        ((u32*)&wB[nt][1])[1] = (u32)f2bf(c0.z) | ((u32)f2bf(c0.w) << 16);
        ((u32*)&wB[nt][1])[2] = (u32)f2bf(c1.x) | ((u32)f2bf(c1.y) << 16);
        ((u32*)&wB[nt][1])[3] = (u32)f2bf(c1.z) | ((u32)f2bf(c1.w) << 16);
        bb[nt] = bm[d];
    }
    __syncthreads();   // B3: section reads done; M0 may overlay

    if (s == 0) {      // normalize -> M0 bf16 (swizzled [qrow][ch]) at h*8KB
        u16* M0 = (u16*)smem + h * 4096;
#pragma unroll
        for (int mt = 0; mt < 2; ++mt)
#pragma unroll
            for (int nt = 0; nt < 2; ++nt)
#pragma unroll
                for (int r = 0; r < 16; ++r) {
                    const int lr = nt * 32 + c31;
                    const int ch = mt * 32 + (r & 3) + 8 * (r >> 2) + 4 * hw;
                    const float v = O[mt][nt][r] * rinv[nt];
                    M0[lr * 64 + (((ch >> 3) ^ (lr & 7)) & 7) * 8 + (ch & 7)] = f2bf(v);
                }
    }
    __syncthreads();   // B4

    // mix: wave w handles rows [16w, 16w+16) (R7-proven)
    const u16* M0r = (const u16*)smem + (wave >> 2) * 4096;
    const int lr = (wave & 3) * 16 + l15;
    const short8 af0 = *(const short8*)&M0r[lr * 64 + ((quad ^ (lr & 7)) & 7) * 8];
    const short8 af1 = *(const short8*)&M0r[lr * 64 + (((4 + quad) ^ (lr & 7)) & 7) * 8];
    float* Mf = (float*)(smem + 16384);      // [128][68] fp32, disjoint from M0
#pragma unroll
    for (int nt = 0; nt < 4; ++nt) {
        f32x4 acc = {0.f, 0.f, 0.f, 0.f};
        acc = MFMA16x32(af0, wB[nt][0], acc, 0, 0, 0);
        acc = MFMA16x32(af1, wB[nt][1], acc, 0, 0, 0);
#pragma unroll
        for (int r = 0; r < 4; ++r) {
            float v = acc[r] + bb[nt];
            v = v > 0.f ? v : 0.f;
            Mf[(wave * 16 + quad * 4 + r) * 68 + nt * 16 + l15] = v;
        }
    }
    __syncthreads();   // B5

    // 2x2 avg pool (== bilinear 2x downsample, half-pixel)
    const int ow = tid & 31;
    const int cb = (tid >> 5) & 15;
#pragma unroll
    for (int i = 0; i < 4; ++i) {
        const int c = cb + i * 16;
        const float v = 0.25f * (Mf[(2 * ow) * 68 + c] + Mf[(2 * ow + 1) * 68 + c]
                               + Mf[(64 + 2 * ow) * 68 + c] + Mf[(65 + 2 * ow) * 68 + c]);
        out[((size_t)(b * 64 + c) * 32 + oh) * 32 + ow] = v;
    }
}

extern "C" void kernel_launch(void* const* d_in, const int* in_sizes, int n_in,
                              void* d_out, int out_size, void* d_ws, size_t ws_size,
                              hipStream_t stream) {
    (void)in_sizes; (void)n_in; (void)out_size; (void)ws_size;
    const float* x  = (const float*)d_in[0];
    const float* wq = (const float*)d_in[1];
    const float* bq = (const float*)d_in[2];
    const float* wk = (const float*)d_in[3];
    const float* bk = (const float*)d_in[4];
    const float* wv = (const float*)d_in[5];
    const float* bv = (const float*)d_in[6];
    const float* wm = (const float*)d_in[7];
    const float* bm = (const float*)d_in[8];

    // ws: Q bf16 [8][4096][64] | KF bf16 [8][128][4][512] | VF bf16 [8][128][4][512] = 12 MB
    u16* Q  = (u16*)d_ws;
    u16* KF = Q + (size_t)8 * NTOK * 64;
    u16* VF = KF + (size_t)8 * NTOK * 64;

    qkv_mfma5<<<512, 256, 0, stream>>>(x, wq, bq, wk, bk, wv, bv, Q, KF, VF);
    attn19<<<256, 512, 0, stream>>>(Q, KF, VF, wm, bm, (float*)d_out);
}